// Round 2
// baseline (105.522 us; speedup 1.0000x reference)
//
#include <hip/hip_runtime.h>
#include <hip/hip_bf16.h>

#ifndef __has_builtin
#define __has_builtin(x) 0
#endif

// ---- problem constants ----
constexpr int B_ = 8, TE_ = 512, TD_ = 128, H_ = 256;
constexpr float TWO_LOG2E = 2.8853900817779268f;   // 2*log2(e)
constexpr float LOG2E = 1.4426950408889634f;

typedef float  vf2    __attribute__((ext_vector_type(2)));
typedef short  bf16x8 __attribute__((ext_vector_type(8)));
typedef float  f32x4  __attribute__((ext_vector_type(4)));

__device__ __forceinline__ float exp2_fast(float x) {
#if __has_builtin(__builtin_amdgcn_exp2f)
  return __builtin_amdgcn_exp2f(x);     // v_exp_f32 (quarter rate)
#else
  return exp2f(x);
#endif
}
__device__ __forceinline__ float rcp_fast(float x) {
#if __has_builtin(__builtin_amdgcn_rcpf)
  return __builtin_amdgcn_rcpf(x);      // v_rcp_f32 (quarter rate)
#else
  return 1.0f / x;
#endif
}
__device__ __forceinline__ vf2 fma2(vf2 a, vf2 b, vf2 c) {
#if __has_builtin(__builtin_elementwise_fma)
  return __builtin_elementwise_fma(a, b, c);   // v_pk_fma_f32
#else
  vf2 r; r.x = __fmaf_rn(a.x, b.x, c.x); r.y = __fmaf_rn(a.y, b.y, c.y); return r;
#endif
}
// split fp32 -> bf16 hi + bf16 lo (x ~= hi + lo to ~2^-16 rel)
__device__ __forceinline__ void bf16split(float x, unsigned short& hi, unsigned short& lo) {
  unsigned u = __float_as_uint(x);
  hi = (unsigned short)(u >> 16);
  float hif = __uint_as_float((unsigned)hi << 16);
  lo = (unsigned short)(__float_as_uint(x - hif) >> 16);
}

// ============== MFMA projection ==============
// ep side now stored TRANSPOSED: ept[B][H][TE] = exp2(2log2e * enc@W), so that
// the fused row kernel reads E coalesced along e. dp stays [B*TD][H].
__global__ __launch_bounds__(256)
void proj_mfma(const float* __restrict__ enc, const float* __restrict__ dec,
               const float* __restrict__ W, const float* __restrict__ U,
               float* __restrict__ ept, float* __restrict__ dp) {
  __shared__ unsigned short Ah[32][40], Al[32][40], Bh[32][40], Bl[32][40];
  const int tid = threadIdx.x;
  const int mt = blockIdx.x;
  const int n0 = blockIdx.y * 32;
  const float* A; const float* Bm; int row0;
  if (mt < 128) { A = enc; Bm = W; row0 = mt * 32; }
  else          { A = dec; Bm = U; row0 = (mt - 128) * 32; }
  const int w = tid >> 6, lane = tid & 63;
  const int mw = (w & 1) * 16, nw = (w >> 1) * 16;
  const int quad = lane >> 4, l16 = lane & 15;
  const int am = tid >> 3, ak = (tid & 7) * 4;
  const int bn = tid & 31, bk = (tid >> 5) * 4;

  f32x4 acc = {0.f, 0.f, 0.f, 0.f};
  for (int k0 = 0; k0 < H_; k0 += 32) {
    float4 a4 = *(const float4*)&A[(long)(row0 + am) * H_ + k0 + ak];
    unsigned short h0, l0, h1, l1, h2, l2, h3, l3;
    bf16split(a4.x, h0, l0); bf16split(a4.y, h1, l1);
    bf16split(a4.z, h2, l2); bf16split(a4.w, h3, l3);
    *(ushort4*)&Ah[am][ak] = make_ushort4(h0, h1, h2, h3);
    *(ushort4*)&Al[am][ak] = make_ushort4(l0, l1, l2, l3);
    float b0 = Bm[(long)(k0 + bk + 0) * H_ + n0 + bn];
    float b1 = Bm[(long)(k0 + bk + 1) * H_ + n0 + bn];
    float b2 = Bm[(long)(k0 + bk + 2) * H_ + n0 + bn];
    float b3 = Bm[(long)(k0 + bk + 3) * H_ + n0 + bn];
    bf16split(b0, h0, l0); bf16split(b1, h1, l1);
    bf16split(b2, h2, l2); bf16split(b3, h3, l3);
    *(ushort4*)&Bh[bn][bk] = make_ushort4(h0, h1, h2, h3);
    *(ushort4*)&Bl[bn][bk] = make_ushort4(l0, l1, l2, l3);
    __syncthreads();
    bf16x8 ah = *(const bf16x8*)&Ah[mw + l16][quad * 8];
    bf16x8 al = *(const bf16x8*)&Al[mw + l16][quad * 8];
    bf16x8 bh = *(const bf16x8*)&Bh[nw + l16][quad * 8];
    bf16x8 bl = *(const bf16x8*)&Bl[nw + l16][quad * 8];
    acc = __builtin_amdgcn_mfma_f32_16x16x32_bf16(ah, bh, acc, 0, 0, 0);
    acc = __builtin_amdgcn_mfma_f32_16x16x32_bf16(ah, bl, acc, 0, 0, 0);
    acc = __builtin_amdgcn_mfma_f32_16x16x32_bf16(al, bh, acc, 0, 0, 0);
    __syncthreads();
  }
  if (mt < 128) {
    // transposed store: ept[b][h][e], b = row0/TE, e = (row0%TE) + m-offset
    const int b = row0 >> 9;
    const int e0 = (row0 & 511) + mw;
    const int hcol = n0 + nw + l16;
#pragma unroll
    for (int r = 0; r < 4; ++r)
      ept[((long)b * H_ + hcol) * TE_ + e0 + quad * 4 + r] =
          exp2_fast(acc[r] * TWO_LOG2E);
  } else {
#pragma unroll
    for (int r = 0; r < 4; ++r)
      dp[(long)(row0 + mw + quad * 4 + r) * H_ + n0 + nw + l16] =
          exp2_fast(acc[r] * TWO_LOG2E);
  }
}

// ============== fused score + softmax ==============
// Block = (b, 4 d-rows), 512 threads = 8 waves. Wave w owns h-slice [32w, 32w+32)
// over ALL 512 e (no cross-wave E-read redundancy) and all 4 d-rows.
// Lane owns e = 4*lane..4*lane+3 and 256+4*lane..+3 (coalesced ept reads).
// score_partial = sum_h (-2 v_h) * rcp(1 + E*D)  (== v.tanh sum minus const,
// softmax-invariant). Partials -> sc_part[8][4][512] LDS -> tree reduce ->
// per-wave softmax -> attn written directly. Kills softmax kernel + sc traffic.
__global__ __launch_bounds__(512)
void row_kernel(const float* __restrict__ ept, const float* __restrict__ dp,
                const float* __restrict__ v, float* __restrict__ attn) {
  __shared__ __align__(16) float d_s[4][256];
  __shared__ __align__(16) float vs[256];
  __shared__ __align__(16) float sc_part[8][4][512];
  const int tid = threadIdx.x;
  const int w = tid >> 6, lane = tid & 63;
  const int b = blockIdx.y;
  const int d0 = blockIdx.x * 4;

  if (tid < 256) {
    int r = tid >> 6, c = (tid & 63) << 2;
    *(float4*)&d_s[r][c] = *(const float4*)&dp[(long)(b * TD_ + d0 + r) * H_ + c];
  } else if (tid < 320) {
    int i = tid - 256;
    float4 v4 = *(const float4*)&v[i << 2];
    float4 o; o.x = -2.f * v4.x; o.y = -2.f * v4.y; o.z = -2.f * v4.z; o.w = -2.f * v4.w;
    *(float4*)&vs[i << 2] = o;
  }
  __syncthreads();

  const float* ebase = ept + (long)b * H_ * TE_;
  const int hbase = w * 32;
  const int el = lane << 2;

  vf2 acc[4][4];   // [d][pair]: pairs 0,1 = e 4l..4l+3 ; 2,3 = 256+4l..+3
#pragma unroll
  for (int d = 0; d < 4; ++d)
#pragma unroll
    for (int p = 0; p < 4; ++p) acc[d][p] = (vf2){0.f, 0.f};

  const vf2 one2 = {1.f, 1.f};
  float4 ea[4], eb[4];
#pragma unroll
  for (int j = 0; j < 4; ++j) {
    ea[j] = *(const float4*)&ebase[(long)(hbase + j) * TE_ + el];
    eb[j] = *(const float4*)&ebase[(long)(hbase + j) * TE_ + 256 + el];
  }
  for (int h = hbase; h < hbase + 32; h += 4) {
    // prefetch next chunk (clamped reload of first chunk on last iter: cheap, safe)
    const int hn = (h + 4 < hbase + 32) ? h + 4 : hbase;
    float4 na[4], nb[4];
#pragma unroll
    for (int j = 0; j < 4; ++j) {
      na[j] = *(const float4*)&ebase[(long)(hn + j) * TE_ + el];
      nb[j] = *(const float4*)&ebase[(long)(hn + j) * TE_ + 256 + el];
    }
    float4 vv = *(const float4*)&vs[h];
#pragma unroll
    for (int d = 0; d < 4; ++d) {
      float4 dd = *(const float4*)&d_s[d][h];
#pragma unroll
      for (int j = 0; j < 4; ++j) {
        float ddj = (j == 0) ? dd.x : (j == 1) ? dd.y : (j == 2) ? dd.z : dd.w;
        float vvj = (j == 0) ? vv.x : (j == 1) ? vv.y : (j == 2) ? vv.z : vv.w;
        vf2 dd2 = {ddj, ddj}, vv2 = {vvj, vvj};
        float4 A4 = ea[j], B4 = eb[j];
        vf2 t0 = fma2((vf2){A4.x, A4.y}, dd2, one2);
        vf2 t1 = fma2((vf2){A4.z, A4.w}, dd2, one2);
        vf2 t2 = fma2((vf2){B4.x, B4.y}, dd2, one2);
        vf2 t3 = fma2((vf2){B4.z, B4.w}, dd2, one2);
        vf2 r0, r1, r2, r3;
        r0.x = rcp_fast(t0.x); r0.y = rcp_fast(t0.y);
        r1.x = rcp_fast(t1.x); r1.y = rcp_fast(t1.y);
        r2.x = rcp_fast(t2.x); r2.y = rcp_fast(t2.y);
        r3.x = rcp_fast(t3.x); r3.y = rcp_fast(t3.y);
        acc[d][0] = fma2(vv2, r0, acc[d][0]);
        acc[d][1] = fma2(vv2, r1, acc[d][1]);
        acc[d][2] = fma2(vv2, r2, acc[d][2]);
        acc[d][3] = fma2(vv2, r3, acc[d][3]);
      }
    }
#pragma unroll
    for (int j = 0; j < 4; ++j) { ea[j] = na[j]; eb[j] = nb[j]; }
  }

  // write this wave's h-slice partials (full [4][512] slice per wave, no races)
#pragma unroll
  for (int d = 0; d < 4; ++d) {
    float4 s0; s0.x = acc[d][0].x; s0.y = acc[d][0].y; s0.z = acc[d][1].x; s0.w = acc[d][1].y;
    float4 s1; s1.x = acc[d][2].x; s1.y = acc[d][2].y; s1.z = acc[d][3].x; s1.w = acc[d][3].y;
    *(float4*)&sc_part[w][d][el] = s0;
    *(float4*)&sc_part[w][d][256 + el] = s1;
  }
  __syncthreads();

  // tree-reduce 8 slices -> sc_part[0]; thread t owns one float4 (1:1, no race)
  {
    const int d = tid >> 7, e4 = (tid & 127) << 2;
    float4 s = *(const float4*)&sc_part[0][d][e4];
#pragma unroll
    for (int sl = 1; sl < 8; ++sl) {
      float4 q = *(const float4*)&sc_part[sl][d][e4];
      s.x += q.x; s.y += q.y; s.z += q.z; s.w += q.w;
    }
    *(float4*)&sc_part[0][d][e4] = s;
  }
  __syncthreads();

  // softmax: waves 0..3, wave w -> d-row w. 8 values per lane.
  if (w < 4) {
    float4 x0 = *(const float4*)&sc_part[0][w][el];
    float4 x1 = *(const float4*)&sc_part[0][w][256 + el];
    float x[8] = {x0.x, x0.y, x0.z, x0.w, x1.x, x1.y, x1.z, x1.w};
    float m = x[0];
#pragma unroll
    for (int k = 1; k < 8; ++k) m = fmaxf(m, x[k]);
#pragma unroll
    for (int off = 32; off; off >>= 1) m = fmaxf(m, __shfl_xor(m, off, 64));
    float s = 0.f;
#pragma unroll
    for (int k = 0; k < 8; ++k) { x[k] = exp2_fast((x[k] - m) * LOG2E); s += x[k]; }
#pragma unroll
    for (int off = 32; off; off >>= 1) s += __shfl_xor(s, off, 64);
    const float r = rcp_fast(s);
    float* po = attn + ((long)b * TD_ + d0 + w) * TE_;
    float4 o0; o0.x = x[0] * r; o0.y = x[1] * r; o0.z = x[2] * r; o0.w = x[3] * r;
    float4 o1; o1.x = x[4] * r; o1.y = x[5] * r; o1.z = x[6] * r; o1.w = x[7] * r;
    *(float4*)&po[el] = o0;
    *(float4*)&po[256 + el] = o1;
  }
}

// ================= MFMA context: ctx[b] = attn[b] @ enc[b] =================
// M=128, N=256, K=512 per batch. Block tile 32m x 32n, K chunks of 32.
// grid (4, 8, 8) = 256 blocks. Split-bf16 3-product scheme.
__global__ __launch_bounds__(256)
void ctx_mfma(const float* __restrict__ attn, const float* __restrict__ enc,
              float* __restrict__ ctx) {
  __shared__ unsigned short Ah[32][40], Al[32][40], Bh[32][40], Bl[32][40];
  const int tid = threadIdx.x;
  const int m0 = blockIdx.x * 32;
  const int n0 = blockIdx.y * 32;
  const int b = blockIdx.z;
  const float* A = attn + (long)b * TD_ * TE_;
  const float* E = enc + (long)b * TE_ * H_;
  const int w = tid >> 6, lane = tid & 63;
  const int mw = (w & 1) * 16, nw = (w >> 1) * 16;
  const int quad = lane >> 4, l16 = lane & 15;
  const int am = tid >> 3, ak = (tid & 7) * 4;
  const int bn = tid & 31, bk = (tid >> 5) * 4;

  f32x4 acc = {0.f, 0.f, 0.f, 0.f};
  for (int k0 = 0; k0 < TE_; k0 += 32) {
    float4 a4 = *(const float4*)&A[(long)(m0 + am) * TE_ + k0 + ak];
    unsigned short h0, l0, h1, l1, h2, l2, h3, l3;
    bf16split(a4.x, h0, l0); bf16split(a4.y, h1, l1);
    bf16split(a4.z, h2, l2); bf16split(a4.w, h3, l3);
    *(ushort4*)&Ah[am][ak] = make_ushort4(h0, h1, h2, h3);
    *(ushort4*)&Al[am][ak] = make_ushort4(l0, l1, l2, l3);
    float b0 = E[(long)(k0 + bk + 0) * H_ + n0 + bn];
    float b1 = E[(long)(k0 + bk + 1) * H_ + n0 + bn];
    float b2 = E[(long)(k0 + bk + 2) * H_ + n0 + bn];
    float b3 = E[(long)(k0 + bk + 3) * H_ + n0 + bn];
    bf16split(b0, h0, l0); bf16split(b1, h1, l1);
    bf16split(b2, h2, l2); bf16split(b3, h3, l3);
    *(ushort4*)&Bh[bn][bk] = make_ushort4(h0, h1, h2, h3);
    *(ushort4*)&Bl[bn][bk] = make_ushort4(l0, l1, l2, l3);
    __syncthreads();
    bf16x8 ah = *(const bf16x8*)&Ah[mw + l16][quad * 8];
    bf16x8 al = *(const bf16x8*)&Al[mw + l16][quad * 8];
    bf16x8 bh = *(const bf16x8*)&Bh[nw + l16][quad * 8];
    bf16x8 bl = *(const bf16x8*)&Bl[nw + l16][quad * 8];
    acc = __builtin_amdgcn_mfma_f32_16x16x32_bf16(ah, bh, acc, 0, 0, 0);
    acc = __builtin_amdgcn_mfma_f32_16x16x32_bf16(ah, bl, acc, 0, 0, 0);
    acc = __builtin_amdgcn_mfma_f32_16x16x32_bf16(al, bh, acc, 0, 0, 0);
    __syncthreads();
  }
#pragma unroll
  for (int r = 0; r < 4; ++r)
    ctx[((long)b * TD_ + m0 + mw + quad * 4 + r) * H_ + n0 + nw + l16] = acc[r];
}

extern "C" void kernel_launch(void* const* d_in, const int* in_sizes, int n_in,
                              void* d_out, int out_size, void* d_ws, size_t ws_size,
                              hipStream_t stream) {
  const float* enc = (const float*)d_in[0];  // [B,TE,H]
  const float* dec = (const float*)d_in[1];  // [B,TD,H]
  const float* Wa  = (const float*)d_in[2];  // [H,H]
  const float* Ua  = (const float*)d_in[3];  // [H,H]
  const float* Va  = (const float*)d_in[4];  // [H,1]

  float* out  = (float*)d_out;
  float* ctx  = out;                           // [B,TD,H]
  float* attn = out + (long)B_ * TD_ * H_;     // [B,TD,TE]

  float* ept = (float*)d_ws;                   // [B,H,TE] transposed exp-proj
  float* dp  = ept + (long)B_ * H_ * TE_;      // [B*TD,H]

  proj_mfma<<<dim3(160, 8), 256, 0, stream>>>(enc, dec, Wa, Ua, ept, dp);
  row_kernel<<<dim3(TD_ / 4, B_), 512, 0, stream>>>(ept, dp, Va, attn);
  ctx_mfma<<<dim3(TD_ / 32, H_ / 32, B_), 256, 0, stream>>>(attn, enc, ctx);
}

// Round 3
// 98.491 us; speedup vs baseline: 1.0714x; 1.0714x over previous
//
#include <hip/hip_runtime.h>
#include <hip/hip_bf16.h>

#ifndef __has_builtin
#define __has_builtin(x) 0
#endif

// ---- problem constants ----
constexpr int B_ = 8, TE_ = 512, TD_ = 128, H_ = 256;
constexpr float TWO_LOG2E = 2.8853900817779268f;   // 2*log2(e)
constexpr float LOG2E = 1.4426950408889634f;

typedef float  vf2    __attribute__((ext_vector_type(2)));
typedef short  bf16x8 __attribute__((ext_vector_type(8)));
typedef float  f32x4  __attribute__((ext_vector_type(4)));

__device__ __forceinline__ float exp2_fast(float x) {
#if __has_builtin(__builtin_amdgcn_exp2f)
  return __builtin_amdgcn_exp2f(x);     // v_exp_f32 (quarter rate)
#else
  return exp2f(x);
#endif
}
__device__ __forceinline__ float rcp_fast(float x) {
#if __has_builtin(__builtin_amdgcn_rcpf)
  return __builtin_amdgcn_rcpf(x);      // v_rcp_f32 (quarter rate)
#else
  return 1.0f / x;
#endif
}
__device__ __forceinline__ vf2 fma2(vf2 a, vf2 b, vf2 c) {
#if __has_builtin(__builtin_elementwise_fma)
  return __builtin_elementwise_fma(a, b, c);   // v_pk_fma_f32
#else
  vf2 r; r.x = __fmaf_rn(a.x, b.x, c.x); r.y = __fmaf_rn(a.y, b.y, c.y); return r;
#endif
}
// split fp32 -> bf16 hi + bf16 lo (x ~= hi + lo to ~2^-16 rel)
__device__ __forceinline__ void bf16split(float x, unsigned short& hi, unsigned short& lo) {
  unsigned u = __float_as_uint(x);
  hi = (unsigned short)(u >> 16);
  float hif = __uint_as_float((unsigned)hi << 16);
  lo = (unsigned short)(__float_as_uint(x - hif) >> 16);
}

// ============== MFMA projection: ep=exp2((enc@W)*2log2e), dp=exp2((dec@U)*2log2e) ==============
// Round-0 proven code. Split-bf16 (3 products). Block tile 32m x 32n, 4 waves,
// K chunks of 32. grid (160, 8) = 1280 blocks.
__global__ __launch_bounds__(256)
void proj_mfma(const float* __restrict__ enc, const float* __restrict__ dec,
               const float* __restrict__ W, const float* __restrict__ U,
               float* __restrict__ ep, float* __restrict__ dp) {
  __shared__ unsigned short Ah[32][40], Al[32][40], Bh[32][40], Bl[32][40];
  const int tid = threadIdx.x;
  const int mt = blockIdx.x;
  const int n0 = blockIdx.y * 32;
  const float* A; const float* Bm; float* C; int row0;
  if (mt < 128) { A = enc; Bm = W; C = ep; row0 = mt * 32; }
  else          { A = dec; Bm = U; C = dp; row0 = (mt - 128) * 32; }
  const int w = tid >> 6, lane = tid & 63;
  const int mw = (w & 1) * 16, nw = (w >> 1) * 16;
  const int quad = lane >> 4, l16 = lane & 15;
  const int am = tid >> 3, ak = (tid & 7) * 4;
  const int bn = tid & 31, bk = (tid >> 5) * 4;

  f32x4 acc = {0.f, 0.f, 0.f, 0.f};
  for (int k0 = 0; k0 < H_; k0 += 32) {
    float4 a4 = *(const float4*)&A[(long)(row0 + am) * H_ + k0 + ak];
    unsigned short h0, l0, h1, l1, h2, l2, h3, l3;
    bf16split(a4.x, h0, l0); bf16split(a4.y, h1, l1);
    bf16split(a4.z, h2, l2); bf16split(a4.w, h3, l3);
    *(ushort4*)&Ah[am][ak] = make_ushort4(h0, h1, h2, h3);
    *(ushort4*)&Al[am][ak] = make_ushort4(l0, l1, l2, l3);
    float b0 = Bm[(long)(k0 + bk + 0) * H_ + n0 + bn];
    float b1 = Bm[(long)(k0 + bk + 1) * H_ + n0 + bn];
    float b2 = Bm[(long)(k0 + bk + 2) * H_ + n0 + bn];
    float b3 = Bm[(long)(k0 + bk + 3) * H_ + n0 + bn];
    bf16split(b0, h0, l0); bf16split(b1, h1, l1);
    bf16split(b2, h2, l2); bf16split(b3, h3, l3);
    *(ushort4*)&Bh[bn][bk] = make_ushort4(h0, h1, h2, h3);
    *(ushort4*)&Bl[bn][bk] = make_ushort4(l0, l1, l2, l3);
    __syncthreads();
    bf16x8 ah = *(const bf16x8*)&Ah[mw + l16][quad * 8];
    bf16x8 al = *(const bf16x8*)&Al[mw + l16][quad * 8];
    bf16x8 bh = *(const bf16x8*)&Bh[nw + l16][quad * 8];
    bf16x8 bl = *(const bf16x8*)&Bl[nw + l16][quad * 8];
    acc = __builtin_amdgcn_mfma_f32_16x16x32_bf16(ah, bh, acc, 0, 0, 0);
    acc = __builtin_amdgcn_mfma_f32_16x16x32_bf16(ah, bl, acc, 0, 0, 0);
    acc = __builtin_amdgcn_mfma_f32_16x16x32_bf16(al, bh, acc, 0, 0, 0);
    __syncthreads();
  }
#pragma unroll
  for (int r = 0; r < 4; ++r)
    C[(long)(row0 + mw + quad * 4 + r) * H_ + n0 + nw + l16] =
        exp2_fast(acc[r] * TWO_LOG2E);
}

// ================= score kernel: t = E*D (no per-elem exp2) =================
// Round-0 proven code. sc_partial[hs][b,d,e] = sum_{h in half} (-2 v_h) *
// rcp(1 + E[e,h]*D[d,h]) == tanh-sum minus const shift (softmax-invariant).
// Tiles 32e x 16d, 256 threads (1e x 2d), grid (16,8,16) = 2048 blocks (8/CU).
__global__ __launch_bounds__(256)
void score_kernel(const float* __restrict__ ep, const float* __restrict__ dp,
                  const float* __restrict__ v, float* __restrict__ sc) {
  __shared__ __align__(16) float eps[32][68];
  __shared__ __align__(16) float dps[16][68];
  __shared__ __align__(16) float vs[64];
  const int tid = threadIdx.x;
  const int bz = blockIdx.z;
  const int b = bz >> 1;
  const int h_lo = (bz & 1) * 128;
  const int e0 = blockIdx.x * 32;
  const int d0 = blockIdx.y * 16;
  const int e = tid & 31;
  const int dg = tid >> 5;
  vf2 acc0 = {0.f, 0.f}, acc1 = {0.f, 0.f};

  for (int h0 = h_lo; h0 < h_lo + 128; h0 += 64) {
#pragma unroll
    for (int i = 0; i < 2; ++i) {
      int idx = tid + i * 256;
      int r = idx >> 4, c = (idx & 15) << 2;
      *(float4*)&eps[r][c] = *(const float4*)&ep[(long)(b * TE_ + e0 + r) * H_ + h0 + c];
    }
    {
      int r = tid >> 4, c = (tid & 15) << 2;
      *(float4*)&dps[r][c] = *(const float4*)&dp[(long)(b * TD_ + d0 + r) * H_ + h0 + c];
    }
    if (tid < 16) {
      float4 v4 = *(const float4*)&v[h0 + tid * 4];
      float4 o; o.x = -2.f * v4.x; o.y = -2.f * v4.y; o.z = -2.f * v4.z; o.w = -2.f * v4.w;
      *(float4*)&vs[tid * 4] = o;
    }
    __syncthreads();
    const vf2 one2 = {1.f, 1.f};
#pragma unroll
    for (int hh = 0; hh < 64; hh += 4) {
      float4 evf = *(const float4*)&eps[e][hh];       // E values
      float4 vvf = *(const float4*)&vs[hh];
      float4 daf = *(const float4*)&dps[dg * 2 + 0][hh];  // D row 0
      float4 dbf = *(const float4*)&dps[dg * 2 + 1][hh];  // D row 1
      vf2 ev0 = {evf.x, evf.y}, ev1 = {evf.z, evf.w};
      vf2 vv0 = {vvf.x, vvf.y}, vv1 = {vvf.z, vvf.w};
      vf2 da0 = {daf.x, daf.y}, da1 = {daf.z, daf.w};
      vf2 db0 = {dbf.x, dbf.y}, db1 = {dbf.z, dbf.w};
      vf2 t0 = ev0 * da0 + one2;   // v_pk_fma: E*D + 1
      vf2 t1 = ev1 * da1 + one2;
      vf2 u0 = ev0 * db0 + one2;
      vf2 u1 = ev1 * db1 + one2;
      vf2 r0, r1, s0, s1;
      r0.x = rcp_fast(t0.x); r0.y = rcp_fast(t0.y);
      r1.x = rcp_fast(t1.x); r1.y = rcp_fast(t1.y);
      s0.x = rcp_fast(u0.x); s0.y = rcp_fast(u0.y);
      s1.x = rcp_fast(u1.x); s1.y = rcp_fast(u1.y);
      acc0 = fma2(vv0, r0, acc0); acc0 = fma2(vv1, r1, acc0);
      acc1 = fma2(vv0, s0, acc1); acc1 = fma2(vv1, s1, acc1);
    }
    __syncthreads();
  }
  long base = ((long)(bz & 1) * B_ * TD_ + (long)b * TD_ + d0 + dg * 2) * TE_ + e0 + e;
  sc[base] = acc0.x + acc0.y;
  sc[base + TE_] = acc1.x + acc1.y;
}

// ========== fused softmax + MFMA context: ctx[b] = softmax(sc) @ enc[b] ==========
// Block (m0=32 d-rows, n0=32 h-cols, b); grid (4,8,8)=256 blocks, 256 threads.
// Phase A: each thread caches its 32-row score slice (16 float4 = 64 vals) in
// registers (x = sc_half0 + sc_half1), 8-lane shuffle-reduce row max, exp2 in
// regs, reduce sum, rs = rcp(sum). Blocks with n0==0 write attn. K-loop stages
// A = xv*rs from REGISTERS (zero global A traffic) and software-prefetches B.
// Kills the softmax launch and the attn HBM round-trip.
__global__ __launch_bounds__(256)
void ctx_sm(const float* __restrict__ sc, const float* __restrict__ enc,
            float* __restrict__ attn, float* __restrict__ ctx) {
  __shared__ unsigned short Ah[32][40], Al[32][40], Bh[32][40], Bl[32][40];
  const int tid = threadIdx.x;
  const int m0 = blockIdx.x * 32;
  const int n0 = blockIdx.y * 32;
  const int b = blockIdx.z;
  const float* s0p = sc + ((long)b * TD_ + m0) * TE_;
  const float* s1p = sc + ((long)B_ * TD_ + (long)b * TD_ + m0) * TE_;
  const float* E = enc + (long)b * TE_ * H_;

  const int w = tid >> 6, lane = tid & 63;
  const int mw = (w & 1) * 16, nw = (w >> 1) * 16;
  const int quad = lane >> 4, l16 = lane & 15;
  const int am = tid >> 3, ak = (tid & 7) * 4;   // A: row am, 4-col chunk ak
  const int bn = tid & 31, bk = (tid >> 5) * 4;  // B: col bn, 4-row chunk bk

  // ---- phase A: softmax stats over registers ----
  // thread (am, t8=ak/4) caches x[am][k*32 + ak .. +3] for k=0..15
  float4 xv[16];
  float mx = -1e30f;
#pragma unroll
  for (int k = 0; k < 16; ++k) {
    long off = (long)am * TE_ + k * 32 + ak;
    float4 a = *(const float4*)&s0p[off];
    float4 c = *(const float4*)&s1p[off];
    float4 x; x.x = a.x + c.x; x.y = a.y + c.y; x.z = a.z + c.z; x.w = a.w + c.w;
    xv[k] = x;
    mx = fmaxf(mx, fmaxf(fmaxf(x.x, x.y), fmaxf(x.z, x.w)));
  }
#pragma unroll
  for (int off = 1; off < 8; off <<= 1) mx = fmaxf(mx, __shfl_xor(mx, off, 64));
  float sum = 0.f;
#pragma unroll
  for (int k = 0; k < 16; ++k) {
    float4 x = xv[k];
    x.x = exp2_fast((x.x - mx) * LOG2E);
    x.y = exp2_fast((x.y - mx) * LOG2E);
    x.z = exp2_fast((x.z - mx) * LOG2E);
    x.w = exp2_fast((x.w - mx) * LOG2E);
    xv[k] = x;
    sum += x.x + x.y + x.z + x.w;
  }
#pragma unroll
  for (int off = 1; off < 8; off <<= 1) sum += __shfl_xor(sum, off, 64);
  const float rs = rcp_fast(sum);

  // attn output (only the n0==0 slice of the grid writes it; values identical
  // across n0 so no race concern even conceptually)
  if (n0 == 0) {
    float* po = attn + ((long)b * TD_ + m0 + am) * TE_;
#pragma unroll
    for (int k = 0; k < 16; ++k) {
      float4 x = xv[k];
      float4 o; o.x = x.x * rs; o.y = x.y * rs; o.z = x.z * rs; o.w = x.w * rs;
      *(float4*)&po[k * 32 + ak] = o;
    }
  }

  // ---- phase B: K-loop, A from regs, B prefetched ----
  float b0, b1, b2, b3;
  b0 = E[(long)(0 + bk + 0) * H_ + n0 + bn];
  b1 = E[(long)(0 + bk + 1) * H_ + n0 + bn];
  b2 = E[(long)(0 + bk + 2) * H_ + n0 + bn];
  b3 = E[(long)(0 + bk + 3) * H_ + n0 + bn];

  f32x4 acc = {0.f, 0.f, 0.f, 0.f};
  for (int k = 0; k < 16; ++k) {
    // stage A from registers (normalized attention weights)
    {
      float4 x = xv[k];
      unsigned short h0, l0, h1, l1, h2, l2, h3, l3;
      bf16split(x.x * rs, h0, l0); bf16split(x.y * rs, h1, l1);
      bf16split(x.z * rs, h2, l2); bf16split(x.w * rs, h3, l3);
      *(ushort4*)&Ah[am][ak] = make_ushort4(h0, h1, h2, h3);
      *(ushort4*)&Al[am][ak] = make_ushort4(l0, l1, l2, l3);
    }
    // stage B from prefetched regs
    {
      unsigned short h0, l0, h1, l1, h2, l2, h3, l3;
      bf16split(b0, h0, l0); bf16split(b1, h1, l1);
      bf16split(b2, h2, l2); bf16split(b3, h3, l3);
      *(ushort4*)&Bh[bn][bk] = make_ushort4(h0, h1, h2, h3);
      *(ushort4*)&Bl[bn][bk] = make_ushort4(l0, l1, l2, l3);
    }
    __syncthreads();
    // issue next B chunk; latency hides under MFMA
    if (k < 15) {
      int k0n = (k + 1) * 32;
      b0 = E[(long)(k0n + bk + 0) * H_ + n0 + bn];
      b1 = E[(long)(k0n + bk + 1) * H_ + n0 + bn];
      b2 = E[(long)(k0n + bk + 2) * H_ + n0 + bn];
      b3 = E[(long)(k0n + bk + 3) * H_ + n0 + bn];
    }
    bf16x8 ah = *(const bf16x8*)&Ah[mw + l16][quad * 8];
    bf16x8 al = *(const bf16x8*)&Al[mw + l16][quad * 8];
    bf16x8 bh = *(const bf16x8*)&Bh[nw + l16][quad * 8];
    bf16x8 bl = *(const bf16x8*)&Bl[nw + l16][quad * 8];
    acc = __builtin_amdgcn_mfma_f32_16x16x32_bf16(ah, bh, acc, 0, 0, 0);
    acc = __builtin_amdgcn_mfma_f32_16x16x32_bf16(ah, bl, acc, 0, 0, 0);
    acc = __builtin_amdgcn_mfma_f32_16x16x32_bf16(al, bh, acc, 0, 0, 0);
    __syncthreads();
  }
#pragma unroll
  for (int r = 0; r < 4; ++r)
    ctx[((long)b * TD_ + m0 + mw + quad * 4 + r) * H_ + n0 + nw + l16] = acc[r];
}

extern "C" void kernel_launch(void* const* d_in, const int* in_sizes, int n_in,
                              void* d_out, int out_size, void* d_ws, size_t ws_size,
                              hipStream_t stream) {
  const float* enc = (const float*)d_in[0];  // [B,TE,H]
  const float* dec = (const float*)d_in[1];  // [B,TD,H]
  const float* Wa  = (const float*)d_in[2];  // [H,H]
  const float* Ua  = (const float*)d_in[3];  // [H,H]
  const float* Va  = (const float*)d_in[4];  // [H,1]

  float* out  = (float*)d_out;
  float* ctx  = out;                           // [B,TD,H]
  float* attn = out + (long)B_ * TD_ * H_;     // [B,TD,TE]

  float* ep = (float*)d_ws;                    // [B*TE,H] = exp2(proj*2log2e)
  float* dp = ep + (long)B_ * TE_ * H_;        // [B*TD,H]
  float* sc = dp + (long)B_ * TD_ * H_;        // [2][B,TD,TE] h-split partials

  proj_mfma<<<dim3(160, 8), 256, 0, stream>>>(enc, dec, Wa, Ua, ep, dp);
  score_kernel<<<dim3(TE_ / 32, TD_ / 16, 2 * B_), 256, 0, stream>>>(ep, dp, Va, sc);
  ctx_sm<<<dim3(TD_ / 32, H_ / 32, B_), 256, 0, stream>>>(sc, enc, attn, ctx);
}